// Round 1
// baseline (402.527 us; speedup 1.0000x reference)
//
#include <hip/hip_runtime.h>
#include <math.h>

// ---------------------------------------------------------------------------
// RPNet: box->xyxy, ROI adaptive max pool (3 levels), hid = rois @ Wh[k] + bh,
// small heads, concat output [16, 242] f32.
//
// ws layout (floats):
//   rois    at 0            : 16 * 53248        = 3,407,872
//   partial at 3,407,872    : 7 * 104 * 16*128  = 1,490,944
//   hid     at 4,898,816    : 7 * 16 * 128      = 14,336
// total 4,913,152 floats = 19.65 MB
// ---------------------------------------------------------------------------

#define B 16
#define F_TOT 53248
#define FC 512           // f-chunk per matmul block
#define NCHUNK (F_TOT / FC)   // 104

__device__ __forceinline__ float clamp01(float v) {
    return fminf(fmaxf(v, 0.0f), 1.0f);
}

// One thread per output bin (b, c, i, j). S = H = W for every level here.
__global__ void roi_kernel(const float* __restrict__ feat,
                           const float* __restrict__ box,
                           float* __restrict__ rois,
                           int C, int S, int fbase) {
    int t = blockIdx.x * blockDim.x + threadIdx.x;
    int total = B * C * 128;
    if (t >= total) return;
    int j = t & 7;
    int i = (t >> 3) & 15;
    int c = (t >> 7) % C;
    int b = t / (C << 7);

    const float* bx = box + b * 4;
    float x = bx[0], y = bx[1], wd = bx[2], ht = bx[3];
    float Sf = (float)S;
    // exact vs numpy: 0.5*wd exact, +/- rounds same as np dot, *2^k exact
    int x1 = (int)(clamp01(x - 0.5f * wd) * Sf);
    int y1 = (int)(clamp01(y - 0.5f * ht) * Sf);
    int x2 = (int)(clamp01(x + 0.5f * wd) * Sf);
    int y2 = (int)(clamp01(y + 0.5f * ht) * Sf);
    x2 = min(x2, S - 1);
    y2 = min(y2, S - 1);
    int h = y2 - y1 + 1;
    int w = x2 - x1 + 1;

    int rs = y1 + (i * h) / 16;
    int re = y1 + ((i + 1) * h + 15) / 16;   // ceil
    int cs = x1 + (j * w) / 8;
    int ce = x1 + ((j + 1) * w + 7) / 8;     // ceil

    const float* fp = feat + ((size_t)(b * C + c)) * S * S;
    float m = -INFINITY;
    for (int r = rs; r < re; ++r) {
        const float* row = fp + r * S;
        for (int cc = cs; cc < ce; ++cc) m = fmaxf(m, row[cc]);
    }
    int f = fbase + (c * 16 + i) * 8 + j;
    rois[(size_t)b * F_TOT + f] = m;
}

// grid (NCHUNK, 7); block 256 = 128 h-lanes x 2 f-phases.
// partial[(k*NCHUNK + cid)][b][h] = sum over f-chunk of rois[b][f]*Wh[k][f][h]
__global__ __launch_bounds__(256) void matmul_part(const float* __restrict__ rois,
                                                   const float* __restrict__ Wh,
                                                   float* __restrict__ partial) {
    __shared__ float rs_[FC * 16];   // [f_local][b] layout, 32 KB
    const int cid = blockIdx.x;
    const int k = blockIdx.y;
    const int f0 = cid * FC;
    const int tid = threadIdx.x;

    // stage rois chunk: conflict-free LDS writes (addr == idx)
    for (int idx = tid; idx < FC * 16; idx += 256) {
        int b = idx & 15;
        int fl = idx >> 4;
        rs_[idx] = rois[(size_t)b * F_TOT + f0 + fl];
    }
    __syncthreads();

    const int h = tid & 127;
    const int fo = tid >> 7;
    const float* wp = Wh + ((size_t)k * F_TOT + f0 + fo) * 128 + h;

    float acc[16];
#pragma unroll
    for (int b = 0; b < 16; ++b) acc[b] = 0.0f;

#pragma unroll 4
    for (int fl = fo; fl < FC; fl += 2) {
        float w = *wp;
        wp += 256;
        const float4* rp = (const float4*)(rs_ + (fl << 4));
        float4 r0 = rp[0], r1 = rp[1], r2 = rp[2], r3 = rp[3];
        acc[0]  += r0.x * w; acc[1]  += r0.y * w; acc[2]  += r0.z * w; acc[3]  += r0.w * w;
        acc[4]  += r1.x * w; acc[5]  += r1.y * w; acc[6]  += r1.z * w; acc[7]  += r1.w * w;
        acc[8]  += r2.x * w; acc[9]  += r2.y * w; acc[10] += r2.z * w; acc[11] += r2.w * w;
        acc[12] += r3.x * w; acc[13] += r3.y * w; acc[14] += r3.z * w; acc[15] += r3.w * w;
    }

    // combine the two f-phases through LDS
    __syncthreads();
    if (fo) {
#pragma unroll
        for (int b = 0; b < 16; ++b) rs_[b * 128 + h] = acc[b];
    }
    __syncthreads();
    if (!fo) {
        float* op = partial + ((size_t)(k * NCHUNK + cid)) * (B * 128);
#pragma unroll
        for (int b = 0; b < 16; ++b) op[b * 128 + h] = acc[b] + rs_[b * 128 + h];
    }
}

// hid[k][b][h] = bh[k][h] + sum_cid partial[k][cid][b][h];  14336 threads
__global__ void reduce_kernel(const float* __restrict__ partial,
                              const float* __restrict__ bh,
                              float* __restrict__ hid) {
    int t = blockIdx.x * blockDim.x + threadIdx.x;  // < 7*16*128 = 14336
    int k = t / (B * 128);
    int r = t % (B * 128);
    int h = r & 127;
    float s = bh[k * 128 + h];
    const float* pp = partial + (size_t)k * NCHUNK * (B * 128) + r;
    for (int cid = 0; cid < NCHUNK; ++cid) s += pp[(size_t)cid * (B * 128)];
    hid[t] = s;
}

// one block per batch row; thread j computes out[b][j], j < 242
__global__ void head_kernel(const float* __restrict__ hid,
                            const float* __restrict__ box,
                            const float* __restrict__ Wp, const float* __restrict__ bp,
                            const float* __restrict__ Wa, const float* __restrict__ ba,
                            const float* __restrict__ Wd, const float* __restrict__ bd,
                            float* __restrict__ out) {
    __shared__ float hs[7 * 128];
    const int b = blockIdx.x;
    const int j = threadIdx.x;
    for (int idx = j; idx < 7 * 128; idx += 256) {
        int k = idx >> 7;
        int h = idx & 127;
        hs[idx] = hid[k * (B * 128) + b * 128 + h];
    }
    __syncthreads();
    if (j >= 242) return;
    float v;
    if (j < 4) {
        v = box[b * 4 + j];
    } else if (j < 42) {
        int o = j - 4;
        v = bp[o];
        for (int h = 0; h < 128; ++h) v += hs[h] * Wp[h * 38 + o];
    } else if (j < 67) {
        int o = j - 42;
        v = ba[o];
        for (int h = 0; h < 128; ++h) v += hs[128 + h] * Wa[h * 25 + o];
    } else {
        int t = j - 67;
        int kk = t / 35;
        int o = t % 35;
        v = bd[kk * 35 + o];
        for (int h = 0; h < 128; ++h) v += hs[(2 + kk) * 128 + h] * Wd[(kk * 128 + h) * 35 + o];
    }
    out[b * 242 + j] = v;
}

extern "C" void kernel_launch(void* const* d_in, const int* in_sizes, int n_in,
                              void* d_out, int out_size, void* d_ws, size_t ws_size,
                              hipStream_t stream) {
    const float* box = (const float*)d_in[0];
    const float* x2  = (const float*)d_in[1];
    const float* x4  = (const float*)d_in[2];
    const float* x6  = (const float*)d_in[3];
    const float* Wh  = (const float*)d_in[4];
    const float* bh  = (const float*)d_in[5];
    const float* Wp  = (const float*)d_in[6];
    const float* bp  = (const float*)d_in[7];
    const float* Wa  = (const float*)d_in[8];
    const float* ba  = (const float*)d_in[9];
    const float* Wd  = (const float*)d_in[10];
    const float* bd  = (const float*)d_in[11];
    float* out = (float*)d_out;

    float* ws = (float*)d_ws;
    float* rois    = ws;                                   // 3,407,872 f
    float* partial = ws + (size_t)B * F_TOT;               // 1,490,944 f
    float* hid     = partial + (size_t)7 * NCHUNK * B * 128; // 14,336 f

    // ROI pooling per level: (C, S, fbase)
    roi_kernel<<<(B * 64  * 128) / 256, 256, 0, stream>>>(x2, box, rois, 64, 128, 0);
    roi_kernel<<<(B * 160 * 128) / 256, 256, 0, stream>>>(x4, box, rois, 160, 64, 8192);
    roi_kernel<<<(B * 192 * 128) / 256, 256, 0, stream>>>(x6, box, rois, 192, 32, 28672);

    // hid partials over f-chunks
    matmul_part<<<dim3(NCHUNK, 7), 256, 0, stream>>>(rois, Wh, partial);
    reduce_kernel<<<(7 * B * 128) / 256, 256, 0, stream>>>(partial, bh, hid);

    // heads + concat
    head_kernel<<<B, 256, 0, stream>>>(hid, box, Wp, bp, Wa, ba, Wd, bd, out);
}

// Round 2
// 401.541 us; speedup vs baseline: 1.0025x; 1.0025x over previous
//
#include <hip/hip_runtime.h>
#include <math.h>

// ---------------------------------------------------------------------------
// RPNet: box->xyxy, ROI adaptive max pool (3 levels, fused), split-K matmul
// hid = rois @ Wh[k] + bh, fused reduce+heads, output [16, 242] f32.
//
// ws layout (floats):
//   rois    at 0         : 16 * 53248       = 3,407,872
//   partial at 3,407,872 : 7 * 104 * 16*128 = 1,490,944
// total 4,898,816 floats = 19.6 MB
// ---------------------------------------------------------------------------

#define B 16
#define F_TOT 53248
#define FC 512               // f-chunk per matmul block
#define NCHUNK (F_TOT / FC)  // 104

__device__ __forceinline__ float clamp01(float v) {
    return fminf(fmaxf(v, 0.0f), 1.0f);
}

// Fused 3-level ROI adaptive max pool. One thread per output bin (b,c,i,j).
// blocks 0..511 -> x2 (C=64,S=128), 512..1791 -> x4 (C=160,S=64),
// 1792..3327 -> x6 (C=192,S=32).
__global__ __launch_bounds__(256) void roi_all(const float* __restrict__ x2,
                                               const float* __restrict__ x4,
                                               const float* __restrict__ x6,
                                               const float* __restrict__ box,
                                               float* __restrict__ rois) {
    const int blk = blockIdx.x;
    const float* feat;
    int C, S, fbase, t;
    if (blk < 512)       { feat = x2; C = 64;  S = 128; fbase = 0;     t = blk * 256 + threadIdx.x; }
    else if (blk < 1792) { feat = x4; C = 160; S = 64;  fbase = 8192;  t = (blk - 512) * 256 + threadIdx.x; }
    else                 { feat = x6; C = 192; S = 32;  fbase = 28672; t = (blk - 1792) * 256 + threadIdx.x; }

    int j = t & 7;
    int i = (t >> 3) & 15;
    int c = (t >> 7) % C;
    int b = t / (C << 7);

    const float* bx = box + b * 4;
    float x = bx[0], y = bx[1], wd = bx[2], ht = bx[3];
    float Sf = (float)S;
    // bit-exact vs np: 0.5*w exact (pow2), fma(x -/+ 0.5w) single-round equals
    // np's x + (-0.5w) since the product is exact; *2^k exact; trunc>=0==floor
    int x1 = (int)(clamp01(x - 0.5f * wd) * Sf);
    int y1 = (int)(clamp01(y - 0.5f * ht) * Sf);
    int x2i = (int)(clamp01(x + 0.5f * wd) * Sf);
    int y2i = (int)(clamp01(y + 0.5f * ht) * Sf);
    x2i = min(x2i, S - 1);
    y2i = min(y2i, S - 1);
    int h = y2i - y1 + 1;
    int w = x2i - x1 + 1;

    int rs = y1 + (i * h) / 16;
    int re = y1 + ((i + 1) * h + 15) / 16;   // ceil
    int cs = x1 + (j * w) / 8;
    int ce = x1 + ((j + 1) * w + 7) / 8;     // ceil

    const float* fp = feat + ((size_t)(b * C + c)) * S * S;
    float m = -INFINITY;
    for (int r = rs; r < re; ++r) {
        const float* row = fp + r * S;
        for (int cc = cs; cc < ce; ++cc) m = fmaxf(m, row[cc]);
    }
    int f = fbase + (c * 16 + i) * 8 + j;
    rois[(size_t)b * F_TOT + f] = m;
}

// grid (NCHUNK, 7); block 256 = 4 f-phases x 64 lanes; each lane owns 2 h cols.
// Wave-instr global loads are 512 B contiguous (one full f-row of Wh).
__global__ __launch_bounds__(256) void matmul_part(const float* __restrict__ rois,
                                                   const float* __restrict__ Wh,
                                                   float* __restrict__ partial) {
    __shared__ float rs_[FC * 16];   // [f_local][b] layout, 32 KB (reused for reduce)
    const int cid = blockIdx.x;
    const int k = blockIdx.y;
    const int f0 = cid * FC;
    const int tid = threadIdx.x;

    // stage rois chunk
    for (int idx = tid; idx < FC * 16; idx += 256) {
        int b = idx & 15;
        int fl = idx >> 4;
        rs_[idx] = rois[(size_t)b * F_TOT + f0 + fl];
    }
    __syncthreads();

    const int fo = tid >> 6;          // 0..3 f-phase
    const int h0 = (tid & 63) * 2;    // 2 h columns per lane
    const float* wp = Wh + ((size_t)k * F_TOT + f0 + fo) * 128 + h0;

    float a0[16], a1[16];
#pragma unroll
    for (int b = 0; b < 16; ++b) { a0[b] = 0.0f; a1[b] = 0.0f; }

#pragma unroll 4
    for (int fl = fo; fl < FC; fl += 4) {
        float2 w = *(const float2*)wp;
        wp += 512;                    // 4 f-rows * 128
        const float4* rp = (const float4*)(rs_ + (fl << 4));
#pragma unroll
        for (int q = 0; q < 4; ++q) {
            float4 rv = rp[q];
            a0[q * 4 + 0] += rv.x * w.x;  a1[q * 4 + 0] += rv.x * w.y;
            a0[q * 4 + 1] += rv.y * w.x;  a1[q * 4 + 1] += rv.y * w.y;
            a0[q * 4 + 2] += rv.z * w.x;  a1[q * 4 + 2] += rv.z * w.y;
            a0[q * 4 + 3] += rv.w * w.x;  a1[q * 4 + 3] += rv.w * w.y;
        }
    }

    // cross-phase reduce through LDS: rs_[fo][b][h], 4*16*128 = 8192 floats
    __syncthreads();
#pragma unroll
    for (int b = 0; b < 16; ++b) {
        *(float2*)(rs_ + fo * 2048 + b * 128 + h0) = make_float2(a0[b], a1[b]);
    }
    __syncthreads();

    float* op = partial + ((size_t)(k * NCHUNK + cid)) * (B * 128);
    for (int idx = tid; idx < 2048; idx += 256) {
        op[idx] = rs_[idx] + rs_[idx + 2048] + rs_[idx + 4096] + rs_[idx + 6144];
    }
}

// Fused split-K reduce + bias + heads + concat. One block per batch row.
__global__ __launch_bounds__(256) void tail_kernel(const float* __restrict__ partial,
                                                   const float* __restrict__ bh,
                                                   const float* __restrict__ box,
                                                   const float* __restrict__ Wp, const float* __restrict__ bp,
                                                   const float* __restrict__ Wa, const float* __restrict__ ba,
                                                   const float* __restrict__ Wd, const float* __restrict__ bd,
                                                   float* __restrict__ out) {
    __shared__ float hs[7 * 128];
    const int b = blockIdx.x;
    const int tid = threadIdx.x;

    for (int idx = tid; idx < 7 * 128; idx += 256) {
        int k = idx >> 7;
        int h = idx & 127;
        const float* pp = partial + (size_t)k * NCHUNK * (B * 128) + b * 128 + h;
        float s = bh[idx];
#pragma unroll 8
        for (int cid = 0; cid < NCHUNK; ++cid) s += pp[(size_t)cid * (B * 128)];
        hs[idx] = s;
    }
    __syncthreads();

    const int j = tid;
    if (j >= 242) return;
    float v;
    if (j < 4) {
        v = box[b * 4 + j];
    } else if (j < 42) {
        int o = j - 4;
        v = bp[o];
        for (int h = 0; h < 128; ++h) v += hs[h] * Wp[h * 38 + o];
    } else if (j < 67) {
        int o = j - 42;
        v = ba[o];
        for (int h = 0; h < 128; ++h) v += hs[128 + h] * Wa[h * 25 + o];
    } else {
        int t = j - 67;
        int kk = t / 35;
        int o = t % 35;
        v = bd[kk * 35 + o];
        for (int h = 0; h < 128; ++h) v += hs[(2 + kk) * 128 + h] * Wd[(kk * 128 + h) * 35 + o];
    }
    out[b * 242 + j] = v;
}

extern "C" void kernel_launch(void* const* d_in, const int* in_sizes, int n_in,
                              void* d_out, int out_size, void* d_ws, size_t ws_size,
                              hipStream_t stream) {
    const float* box = (const float*)d_in[0];
    const float* x2  = (const float*)d_in[1];
    const float* x4  = (const float*)d_in[2];
    const float* x6  = (const float*)d_in[3];
    const float* Wh  = (const float*)d_in[4];
    const float* bh  = (const float*)d_in[5];
    const float* Wp  = (const float*)d_in[6];
    const float* bp  = (const float*)d_in[7];
    const float* Wa  = (const float*)d_in[8];
    const float* ba  = (const float*)d_in[9];
    const float* Wd  = (const float*)d_in[10];
    const float* bd  = (const float*)d_in[11];
    float* out = (float*)d_out;

    float* ws = (float*)d_ws;
    float* rois    = ws;                      // 3,407,872 f
    float* partial = ws + (size_t)B * F_TOT;  // 1,490,944 f

    roi_all<<<3328, 256, 0, stream>>>(x2, x4, x6, box, rois);
    matmul_part<<<dim3(NCHUNK, 7), 256, 0, stream>>>(rois, Wh, partial);
    tail_kernel<<<B, 256, 0, stream>>>(partial, bh, box, Wp, bp, Wa, ba, Wd, bd, out);
}